// Round 11
// baseline (163.932 us; speedup 1.0000x reference)
//
#include <hip/hip_runtime.h>
#include <hip/hip_bf16.h>
#include <stdint.h>

// B=4, C=256, N=4096, dk=32
typedef float f32x16 __attribute__((ext_vector_type(16)));
typedef short bf16x8 __attribute__((ext_vector_type(8)));

#define L2E 1.4426950408889634f
#define ROWPAT(r, hi) (((r) & 3) + 8 * ((r) >> 2) + 4 * (hi))

// ws layout (bytes): Wcb 160KB | qbuf 1MB | kbuf 1MB | vbuf 8MB
#define WCATB_OFF 0u
#define QBUF_OFF  163840u
#define KBUF_OFF  1212416u
#define VBUF_OFF  2260992u

static __device__ __forceinline__ ushort f2bf(float f) {
    union { float f; uint32_t u; } v; v.f = f;
    uint32_t u = v.u;
    return (ushort)((u + 0x7fffu + ((u >> 16) & 1u)) >> 16);
}

static __device__ __forceinline__ uint32_t cvtpk(float lo, float hi) {
    uint32_t r;
    asm volatile("v_cvt_pk_bf16_f32 %0, %1, %2" : "=v"(r) : "v"(lo), "v"(hi));
    return r;
}
// p[j] at D-pattern m' = (j&3)+8*(j>>2)+4*hi; -> B-frag words for 16 keys.
static __device__ __forceinline__ bf16x8 packP(float p0, float p1, float p2, float p3,
                                               float p4, float p5, float p6, float p7) {
    uint32_t a0 = cvtpk(p0, p1), a1 = cvtpk(p2, p3);
    uint32_t b0 = cvtpk(p4, p5), b1 = cvtpk(p6, p7);
    auto s0 = __builtin_amdgcn_permlane32_swap(a0, b0, false, false);
    auto s1 = __builtin_amdgcn_permlane32_swap(a1, b1, false, false);
    union { uint32_t u[4]; bf16x8 v; } pk;
    pk.u[0] = s0[0];
    pk.u[1] = s1[0];
    pk.u[2] = s0[1];
    pk.u[3] = s1[1];
    return pk.v;
}

// ---------------- prep: Wcat_bf16 [320][256] ----------------
__global__ void prep_kernel(const float* __restrict__ Wq, const float* __restrict__ Wk,
                            const float* __restrict__ Wv, ushort* __restrict__ Wcb) {
    int row = blockIdx.x, c = threadIdx.x;
    float v;
    if (row < 32)      v = Wq[row * 256 + c];
    else if (row < 64) v = Wk[(row - 32) * 256 + c];
    else               v = Wv[(row - 64) * 256 + c];
    Wcb[row * 256 + c] = f2bf(v);
}

// ---------------- fused proj: x -> (transpose in LDS) -> Q,K,V --------------
// grid 512 = 4b x 128 n-tiles(32). Block 256 thr = 4 waves; 10 MFMA chains
// (Q, K, V0..V7) distributed cc = w, w+4, w+8. Q pre-scaled by log2(e).
__global__ __launch_bounds__(256)
void fproj_kernel(const float* __restrict__ x, const ushort* __restrict__ Wcb,
                  const float* __restrict__ bq, const float* __restrict__ bk,
                  const float* __restrict__ bv,
                  ushort* __restrict__ qbuf, ushort* __restrict__ kbuf,
                  ushort* __restrict__ vbuf) {
    __shared__ ushort xt[32 * 264];   // [n][c] bf16, stride 264 (16B-aligned rows)
    const int tid = threadIdx.x;
    const int b = blockIdx.x >> 7;
    const int n0 = (blockIdx.x & 127) << 5;

    const float* xb = x + (((size_t)b) << 20) + n0;   // b*256*4096
    #pragma unroll
    for (int i = 0; i < 8; ++i) {
        int task = tid + (i << 8);
        int c = task >> 3, seg = task & 7;
        float4 v = *(const float4*)(xb + (size_t)c * 4096 + seg * 4);
        xt[(seg * 4 + 0) * 264 + c] = f2bf(v.x);
        xt[(seg * 4 + 1) * 264 + c] = f2bf(v.y);
        xt[(seg * 4 + 2) * 264 + c] = f2bf(v.z);
        xt[(seg * 4 + 3) * 264 + c] = f2bf(v.w);
    }
    __syncthreads();

    const int w = tid >> 6, l = tid & 63;
    const int l31 = l & 31, hi = l >> 5;

    for (int cc = w; cc < 10; cc += 4) {
        const int wbase = (cc < 2) ? cc * 32 : (cc - 2) * 32 + 64;
        const ushort* wrow = Wcb + (size_t)(wbase + l31) * 256;
        f32x16 acc = (f32x16)0.0f;
        if (cc < 2) {
            // Q/K: A = xt rows (n), B = W rows (m); D[n][m], col=l31=m
            #pragma unroll
            for (int kk = 0; kk < 16; ++kk) {
                bf16x8 xf = *(const bf16x8*)&xt[l31 * 264 + kk * 16 + hi * 8];
                bf16x8 wf = *(const bf16x8*)&wrow[kk * 16 + hi * 8];
                acc = __builtin_amdgcn_mfma_f32_32x32x16_bf16(xf, wf, acc, 0, 0, 0);
            }
            const float bias = (cc == 0) ? bq[l31] : bk[l31];
            const float scale = (cc == 0) ? L2E : 1.0f;
            ushort* dst = (cc == 0) ? qbuf : kbuf;
            #pragma unroll
            for (int r = 0; r < 16; ++r) {
                int n = n0 + ROWPAT(r, hi);
                dst[((size_t)((b << 12) + n)) * 32 + l31] = f2bf((acc[r] + bias) * scale);
            }
        } else {
            // V: A = W rows (c), B = xt rows (n); D[c][n], col=l31=n
            #pragma unroll
            for (int kk = 0; kk < 16; ++kk) {
                bf16x8 wf = *(const bf16x8*)&wrow[kk * 16 + hi * 8];
                bf16x8 xf = *(const bf16x8*)&xt[l31 * 264 + kk * 16 + hi * 8];
                acc = __builtin_amdgcn_mfma_f32_32x32x16_bf16(wf, xf, acc, 0, 0, 0);
            }
            #pragma unroll
            for (int r = 0; r < 16; ++r) {
                int c = (wbase - 64) + ROWPAT(r, hi);
                vbuf[((size_t)(b * 256 + c)) * 4096 + n0 + l31] = f2bf(acc[r] + bv[c]);
            }
        }
    }
}

// ---------------- attention v8: direct-from-L2 K/V, zero main-loop LDS ------
// grid 512 (XCD-clustered) = 4b x 128 qtiles(32q); block 256 = 4 waves.
// wave (kh,cp) owns keys kh*32+cp*16..+15. K [n][32] and V [c][n] global
// layouts ARE the swapped-MFMA A-frag layouts -> direct 16B loads, no LDS
// staging, no main-loop barriers (waves free-run; R10 was LDS-BW-bound at
// ~82 B/cyc). Register prefetch one key-tile ahead (A/B named buffers).
__global__ __launch_bounds__(256, 2)
void attn_kernel(const ushort* __restrict__ qbuf, const ushort* __restrict__ kbuf,
                 const ushort* __restrict__ vbuf, const float* __restrict__ x,
                 const float* __restrict__ gammap, float* __restrict__ out) {
    __shared__ float scr[16384];      // 64 KB combine scratch
    __shared__ float dlds[2][2][32];

    const int tid = threadIdx.x;
    const int bid = blockIdx.x;
    const int work = (bid & 7) * 64 + (bid >> 3);   // XCD-cluster
    const int b = work >> 7;
    const int qbase = (work & 127) << 5;
    const int w = tid >> 6, l = tid & 63;
    const int l31 = l & 31, hi = l >> 5;
    const int kh = w >> 1, cp = w & 1;
    const int cps = __builtin_amdgcn_readfirstlane(cp);

    // Q B-frags (col=q=l31, k = 16*kst + 8*hi + j); Q pre-scaled by log2(e)
    const ushort* qrow = qbuf + ((size_t)((b << 12) + qbase + l31)) * 32;
    const bf16x8 qf0 = *(const bf16x8*)&qrow[hi * 8];
    const bf16x8 qf1 = *(const bf16x8*)&qrow[16 + hi * 8];

    // direct per-lane operand pointers
    const ushort* kptr = kbuf + ((size_t)b << 12) * 32
                       + (size_t)(kh * 32 + l31) * 32 + hi * 8;       // + m0*32 per tile
    const int vcol = kh * 32 + cp * 16 + hi * 8;
    const ushort* vptr = vbuf + ((size_t)b << 8) * 4096
                       + (size_t)l31 * 4096 + vcol;                   // + ch*131072 + m0

    f32x16 acc[8];
    #pragma unroll
    for (int ch = 0; ch < 8; ++ch) acc[ch] = (f32x16)0.0f;
    float dsum = 0.f;

    union u4bf { uint4 u; bf16x8 v; };
    uint4 kA[2], kB[2], vA[8], vB[8];

    // prefetch tile 0 -> A
    kA[0] = *(const uint4*)(kptr);
    kA[1] = *(const uint4*)(kptr + 16);
    #pragma unroll
    for (int ch = 0; ch < 8; ++ch)
        vA[ch] = *(const uint4*)(vptr + (size_t)ch * 131072);

#define ATTN_STEP(KR, VR)                                                          \
    {                                                                              \
        u4bf kf0, kf1;                                                             \
        kf0.u = KR[0]; kf1.u = KR[1];                                              \
        f32x16 sT = __builtin_amdgcn_mfma_f32_32x32x16_bf16(kf0.v, qf0,            \
                                                            (f32x16)0.0f, 0, 0, 0);\
        sT = __builtin_amdgcn_mfma_f32_32x32x16_bf16(kf1.v, qf1, sT, 0, 0, 0);     \
        float p[8];                                                                \
        if (cps) {                                                                 \
            p[0] = exp2f(sT[8]);  p[1] = exp2f(sT[9]);                             \
            p[2] = exp2f(sT[10]); p[3] = exp2f(sT[11]);                            \
            p[4] = exp2f(sT[12]); p[5] = exp2f(sT[13]);                            \
            p[6] = exp2f(sT[14]); p[7] = exp2f(sT[15]);                            \
        } else {                                                                   \
            p[0] = exp2f(sT[0]);  p[1] = exp2f(sT[1]);                             \
            p[2] = exp2f(sT[2]);  p[3] = exp2f(sT[3]);                             \
            p[4] = exp2f(sT[4]);  p[5] = exp2f(sT[5]);                             \
            p[6] = exp2f(sT[6]);  p[7] = exp2f(sT[7]);                             \
        }                                                                          \
        dsum += ((p[0] + p[1]) + (p[2] + p[3])) + ((p[4] + p[5]) + (p[6] + p[7])); \
        bf16x8 pf = packP(p[0], p[1], p[2], p[3], p[4], p[5], p[6], p[7]);         \
        __builtin_amdgcn_s_setprio(1);                                             \
        _Pragma("unroll")                                                          \
        for (int ch = 0; ch < 8; ++ch) {                                           \
            u4bf vf; vf.u = VR[ch];                                                \
            acc[ch] = __builtin_amdgcn_mfma_f32_32x32x16_bf16(vf.v, pf,            \
                                                              acc[ch], 0, 0, 0);   \
        }                                                                          \
        __builtin_amdgcn_s_setprio(0);                                             \
    }

    for (int it = 0; it < 64; it += 2) {
        // load tile it+1 -> B
        {
            const size_t m0 = (size_t)(it + 1) << 6;
            kB[0] = *(const uint4*)(kptr + m0 * 32);
            kB[1] = *(const uint4*)(kptr + m0 * 32 + 16);
            #pragma unroll
            for (int ch = 0; ch < 8; ++ch)
                vB[ch] = *(const uint4*)(vptr + (size_t)ch * 131072 + m0);
        }
        ATTN_STEP(kA, vA);
        // load tile it+2 -> A
        if (it < 62) {
            const size_t m0 = (size_t)(it + 2) << 6;
            kA[0] = *(const uint4*)(kptr + m0 * 32);
            kA[1] = *(const uint4*)(kptr + m0 * 32 + 16);
            #pragma unroll
            for (int ch = 0; ch < 8; ++ch)
                vA[ch] = *(const uint4*)(vptr + (size_t)ch * 131072 + m0);
        }
        ATTN_STEP(kB, vB);
    }
#undef ATTN_STEP

    // ---- combine 4 partial accumulators + epilogue ----
    const float gam = gammap[0];
    float dall = dsum + __shfl_xor(dsum, 32);
    if (l < 32) dlds[kh][cp][l31] = dall;
    __syncthreads();
    if (kh == 1) {
        #pragma unroll
        for (int ch = 0; ch < 8; ++ch)
            #pragma unroll
            for (int r = 0; r < 16; ++r)
                scr[(((cp * 8 + ch) * 16 + r) << 6) + l] = acc[ch][r];
    }
    __syncthreads();
    if (kh == 0) {
        #pragma unroll
        for (int ch = 0; ch < 8; ++ch)
            #pragma unroll
            for (int r = 0; r < 16; ++r)
                acc[ch][r] += scr[(((cp * 8 + ch) * 16 + r) << 6) + l];
    }
    __syncthreads();
    if (kh == 0 && cp == 1) {
        #pragma unroll
        for (int ch = 0; ch < 8; ++ch)
            #pragma unroll
            for (int r = 0; r < 16; ++r)
                scr[((ch * 16 + r) << 6) + l] = acc[ch][r];
    }
    __syncthreads();
    if (kh == 0 && cp == 0) {
        #pragma unroll
        for (int ch = 0; ch < 8; ++ch)
            #pragma unroll
            for (int r = 0; r < 16; ++r) {
                float o = acc[ch][r] + scr[((ch * 16 + r) << 6) + l];
                scr[((ch * 16 + r) << 6) + l] = o;
            }
    }
    __syncthreads();
    const float denom = dlds[0][0][l31] + dlds[0][1][l31] + dlds[1][0][l31] + dlds[1][1][l31];
    const float ginv = gam / denom;
    const float* xb2 = x + (((size_t)b) << 8) * 4096;
    float* ob = out + (((size_t)b) << 8) * 4096;
    const int q = qbase + l31;
    #pragma unroll
    for (int j = 0; j < 2; ++j) {
        const int ch = w * 2 + j;
        #pragma unroll
        for (int r = 0; r < 16; ++r) {
            int c = ch * 32 + ROWPAT(r, hi);
            float o = scr[((ch * 16 + r) << 6) + l];
            size_t idx = (size_t)c * 4096 + q;
            ob[idx] = o * ginv + xb2[idx];
        }
    }
}

extern "C" void kernel_launch(void* const* d_in, const int* in_sizes, int n_in,
                              void* d_out, int out_size, void* d_ws, size_t ws_size,
                              hipStream_t stream) {
    (void)in_sizes; (void)n_in; (void)out_size; (void)ws_size;
    const float* x     = (const float*)d_in[0];
    const float* Wq    = (const float*)d_in[1];
    const float* bq    = (const float*)d_in[2];
    const float* Wk    = (const float*)d_in[3];
    const float* bk    = (const float*)d_in[4];
    const float* Wv    = (const float*)d_in[5];
    const float* bv    = (const float*)d_in[6];
    const float* gamma = (const float*)d_in[7];
    float* out = (float*)d_out;

    char* ws = (char*)d_ws;
    ushort* Wcb  = (ushort*)(ws + WCATB_OFF);
    ushort* qbuf = (ushort*)(ws + QBUF_OFF);
    ushort* kbuf = (ushort*)(ws + KBUF_OFF);
    ushort* vbuf = (ushort*)(ws + VBUF_OFF);

    prep_kernel<<<320, 256, 0, stream>>>(Wq, Wk, Wv, Wcb);
    fproj_kernel<<<512, 256, 0, stream>>>(x, Wcb, bq, bk, bv, qbuf, kbuf, vbuf);
    attn_kernel<<<512, 256, 0, stream>>>(qbuf, kbuf, vbuf, x, gamma, out);
}